// Round 3
// baseline (1542.501 us; speedup 1.0000x reference)
//
#include <hip/hip_runtime.h>
#include <hip/hip_bf16.h>

#define HWN    1024     // H*W spatial tokens
#define CCH    512      // channels
#define NBATCH 16
#define NGROUP 32
#define EPSV   1e-5f

using bf16 = __hip_bfloat16;

// Runtime-dtyped element access: c==1 -> fp32, c==0 -> bf16.
__device__ __forceinline__ float ldv(const void* p, long i, int c) {
    return c ? ((const float*)p)[i] : __bfloat162float(((const bf16*)p)[i]);
}
__device__ __forceinline__ void stv(void* p, long i, int c, float v) {
    if (c) ((float*)p)[i] = v;
    else   ((bf16*)p)[i]  = __float2bfloat16(v);
}

// ---------------------------------------------------------------------------
// Storage dtype detector. True bf16 data: every 16-bit half has a sane
// exponent (N(0,1) -> e in ~[107,129]). fp32 data read as bf16: even halves
// are fp32 low-mantissa bits -> exponent ~uniform -> ~14% sane. flag=1 => f32.
// ---------------------------------------------------------------------------
__global__ __launch_bounds__(256) void detect_kernel(const void* __restrict__ x,
                                                     int* __restrict__ flag)
{
    const int tid = threadIdx.x;
    const unsigned short* h = (const unsigned short*)x;
    int ok = 0;
    for (int i = tid; i < 4096; i += 256) {
        int e = (h[2 * i] >> 7) & 0xFF;      // even-index bf16 slots
        if (e >= 100 && e <= 135) ok++;
    }
    __shared__ int red[256];
    red[tid] = ok; __syncthreads();
    for (int off = 128; off > 0; off >>= 1) {
        if (tid < off) red[tid] += red[tid + off];
        __syncthreads();
    }
    if (tid == 0) flag[0] = (red[0] < 2458) ? 1 : 0;   // <60% sane => fp32
}

// ---------------------------------------------------------------------------
// GroupNorm stats: one block per (batch, group) -> (mean, rstd).
// ---------------------------------------------------------------------------
__global__ __launch_bounds__(256) void gn_stats_kernel(const void* __restrict__ x,
                                                       const int* __restrict__ flag,
                                                       float2* __restrict__ stats)
{
    const int f = flag[0];
    const int b = blockIdx.x >> 5, g = blockIdx.x & 31;
    const long base = ((long)b * CCH + (long)g * (CCH / NGROUP)) * HWN;
    const int tid = threadIdx.x;
    const int n = (CCH / NGROUP) * HWN;       // 16384
    float s = 0.f, ss = 0.f;
    for (int i = tid; i < n; i += 256) {
        float v = ldv(x, base + i, f);
        s += v; ss += v * v;
    }
    __shared__ float r1[256], r2[256];
    r1[tid] = s; r2[tid] = ss; __syncthreads();
    for (int off = 128; off > 0; off >>= 1) {
        if (tid < off) { r1[tid] += r1[tid + off]; r2[tid] += r2[tid + off]; }
        __syncthreads();
    }
    if (tid == 0) {
        float mean = r1[0] / n;
        float var  = r2[0] / n - mean * mean;
        stats[blockIdx.x] = make_float2(mean, rsqrtf(var + EPSV));
    }
}

// ---------------------------------------------------------------------------
// Generic tiled GEMM, fp32 accumulate, runtime dtypes (codes: 0 bf16, 1 f32,
// 2 = take from flag). TA: A stored [K,M]. TB: B stored [N,K].
// GNB: apply GroupNorm+SiLU to B elements during staging (B = x, rows = chan).
// Batch via zA = z0 + blockIdx.z, element strides sA/sB/sC/sR (0 = shared).
// Tile 64x64, K-tile 16, 256 threads, 4x4 per thread.
// ---------------------------------------------------------------------------
#define TILE 64
#define KT   16

template<bool TA, bool TB, bool GNB>
__global__ __launch_bounds__(256)
void gemm_kernel(const void* __restrict__ A, const void* __restrict__ B,
                 void* __restrict__ C, int M, int N, int K,
                 long sA, long sB, long sC,
                 int aT, int bT, int cT, const int* __restrict__ flag,
                 const void* __restrict__ bias, int biasT,
                 const void* __restrict__ resid, long sR, int rT,
                 float alpha, const float2* __restrict__ stats,
                 const void* __restrict__ gamma, const void* __restrict__ beta,
                 int gbT, int z0)
{
    const int f  = flag ? flag[0] : 0;
    const int ac = (aT == 2) ? f : aT;
    const int bc = (bT == 2) ? f : bT;
    const int cc = (cT == 2) ? f : cT;
    const int gb = (gbT == 2) ? f : gbT;
    const int zA = z0 + blockIdx.z;
    const long aOff = (long)zA * sA;
    const long bOff = (long)zA * sB;
    const long cOff = (long)zA * sC;
    const long rOff = (long)zA * sR;

    __shared__ float As[KT][TILE + 4];
    __shared__ float Bs[KT][TILE + 4];

    const int tid = threadIdx.x;
    const int m0 = blockIdx.y * TILE;
    const int n0 = blockIdx.x * TILE;
    const int tx = tid & 15;    // -> n
    const int ty = tid >> 4;    // -> m

    float acc[4][4] = {};

    for (int kk = 0; kk < K; kk += KT) {
        if (TA) {
            const int m = tid & 63, kq = tid >> 6;
            #pragma unroll
            for (int r = 0; r < 4; ++r)
                As[kq + 4 * r][m] =
                    ldv(A, aOff + (long)(kk + kq + 4 * r) * M + (m0 + m), ac);
        } else {
            const int kq = tid & 15, mi = tid >> 4;
            #pragma unroll
            for (int r = 0; r < 4; ++r)
                As[kq][mi + 16 * r] =
                    ldv(A, aOff + (long)(m0 + mi + 16 * r) * K + (kk + kq), ac);
        }
        if (TB) {
            const int kq = tid & 15, ni = tid >> 4;
            #pragma unroll
            for (int r = 0; r < 4; ++r)
                Bs[kq][ni + 16 * r] =
                    ldv(B, bOff + (long)(n0 + ni + 16 * r) * K + (kk + kq), bc);
        } else {
            const int nn = tid & 63, kq = tid >> 6;
            #pragma unroll
            for (int r = 0; r < 4; ++r) {
                const int row = kk + kq + 4 * r;          // channel for GNB
                float vv = ldv(B, bOff + (long)row * N + (n0 + nn), bc);
                if (GNB) {
                    float2 st = stats[zA * NGROUP + (row >> 4)];
                    float ga = ldv(gamma, row, gb);
                    float be = ldv(beta,  row, gb);
                    vv = (vv - st.x) * st.y * ga + be;
                    vv = vv / (1.f + __expf(-vv));        // SiLU
                }
                Bs[kq + 4 * r][nn] = vv;
            }
        }
        __syncthreads();

        #pragma unroll
        for (int k = 0; k < KT; ++k) {
            float a[4], bv[4];
            #pragma unroll
            for (int i = 0; i < 4; ++i) a[i]  = As[k][ty * 4 + i];
            #pragma unroll
            for (int j = 0; j < 4; ++j) bv[j] = Bs[k][tx * 4 + j];
            #pragma unroll
            for (int i = 0; i < 4; ++i)
                #pragma unroll
                for (int j = 0; j < 4; ++j)
                    acc[i][j] += a[i] * bv[j];
        }
        __syncthreads();
    }

    #pragma unroll
    for (int i = 0; i < 4; ++i) {
        const int m = m0 + ty * 4 + i;
        const float bi = bias ? ldv(bias, m, (biasT == 2) ? f : biasT) : 0.f;
        #pragma unroll
        for (int j = 0; j < 4; ++j) {
            const int n = n0 + tx * 4 + j;
            float v = alpha * acc[i][j] + bi;
            if (resid) v += ldv(resid, rOff + (long)m * N + n, (rT == 2) ? f : rT);
            stv(C, cOff + (long)m * N + n, cc, v);
        }
    }
}

// ---------------------------------------------------------------------------
// Row softmax over 1024 fp32 elements, in place. One block per row.
// ---------------------------------------------------------------------------
__global__ __launch_bounds__(256)
void softmax_kernel(float* __restrict__ sc)
{
    float* p = sc + (long)blockIdx.x * HWN;
    const int tid = threadIdx.x;
    float v[4];
    float mx = -1e30f;
    #pragma unroll
    for (int i = 0; i < 4; ++i) { v[i] = p[tid + 256 * i]; mx = fmaxf(mx, v[i]); }

    __shared__ float red[256];
    red[tid] = mx; __syncthreads();
    for (int off = 128; off > 0; off >>= 1) {
        if (tid < off) red[tid] = fmaxf(red[tid], red[tid + off]);
        __syncthreads();
    }
    mx = red[0]; __syncthreads();

    float s = 0.f;
    #pragma unroll
    for (int i = 0; i < 4; ++i) { v[i] = __expf(v[i] - mx); s += v[i]; }
    red[tid] = s; __syncthreads();
    for (int off = 128; off > 0; off >>= 1) {
        if (tid < off) red[tid] += red[tid + off];
        __syncthreads();
    }
    const float inv = 1.f / red[0];
    #pragma unroll
    for (int i = 0; i < 4; ++i) p[tid + 256 * i] = v[i] * inv;
}

// ---------------------------------------------------------------------------
extern "C" void kernel_launch(void* const* d_in, const int* in_sizes, int n_in,
                              void* d_out, int out_size, void* d_ws, size_t ws_size,
                              hipStream_t stream)
{
    // ---- input order (insertion per docs; alphabetical fallback) ----
    const long NX = (long)NBATCH * CCH * HWN;   // 8388608
    int ix, iWq, ibq, iWk, ibk, iWv, ibv, iWo, ibo, iga, ibe;
    if (in_sizes[0] == NX) {       // insertion: x,Wq,bq,Wk,bk,Wv,bv,Wo,bo,gamma,beta
        ix = 0; iWq = 1; ibq = 2; iWk = 3; ibk = 4; iWv = 5; ibv = 6;
        iWo = 7; ibo = 8; iga = 9; ibe = 10;
    } else {                        // alphabetical: Wk,Wo,Wq,Wv,beta,bk,bo,bq,bv,gamma,x
        iWk = 0; iWo = 1; iWq = 2; iWv = 3; ibe = 4; ibk = 5; ibo = 6;
        ibq = 7; ibv = 8; iga = 9; ix = 10;
    }
    const void* x     = d_in[ix];
    const void* Wq    = d_in[iWq];
    const void* bq    = d_in[ibq];
    const void* Wk    = d_in[iWk];
    const void* bk    = d_in[ibk];
    const void* Wv    = d_in[iWv];
    const void* bv    = d_in[ibv];
    const void* Wo    = d_in[iWo];
    const void* bo    = d_in[ibo];
    const void* gamma = d_in[iga];
    const void* beta  = d_in[ibe];

    const long CHW = (long)CCH * HWN;           // 524288 elem/batch
    const long NN  = (long)HWN * HWN;           // 1048576 scores/batch
    const size_t MB = 1u << 20;
    char* ws = (char*)d_ws;

    const bool batched = ws_size >= 112 * MB + 16384;

    // qkv always: q@0, k@16M, v@32M (bf16, 16 MB each)
    bf16* q = (bf16*)(ws);
    bf16* k = (bf16*)(ws + 16 * MB);
    bf16* v = (bf16*)(ws + 32 * MB);
    float* sc;  bf16* hh;  float2* stats;  int* flag;
    if (batched) {
        sc    = (float*)(ws + 48 * MB);          // 64 MB
        hh    = q;                               // q dead after scores GEMM
        stats = (float2*)(ws + 112 * MB);
        flag  = (int*)(ws + 112 * MB + 8192);
    } else {
        sc    = (float*)(ws + 48 * MB);          // 4 MB (one batch)
        hh    = (bf16*)(ws + 52 * MB);           // 1 MB (one batch)
        stats = (float2*)(ws + 53 * MB);
        flag  = (int*)(ws + 53 * MB + 8192);
    }

    dim3 blk(256);
    const float scale = 0.044194173824159216f;   // 512^-0.5
    const void* NUL = nullptr;

    // 1) dtype detect + GN stats
    detect_kernel<<<dim3(1), blk, 0, stream>>>(x, flag);
    gn_stats_kernel<<<dim3(NBATCH * NGROUP), blk, 0, stream>>>(x, flag, stats);

    // 2) QKV projections with fused GN+SiLU on B: C[o,i] = W[o,c] gn(x)[c,i] + b
    dim3 gqkv(HWN / TILE, CCH / TILE, NBATCH);
    gemm_kernel<false, false, true><<<gqkv, blk, 0, stream>>>(Wq, x, q,
        CCH, HWN, CCH, 0L, CHW, CHW, 2, 2, 0, flag, bq, 2, NUL, 0L, 0, 1.f,
        stats, gamma, beta, 2, 0);
    gemm_kernel<false, false, true><<<gqkv, blk, 0, stream>>>(Wk, x, k,
        CCH, HWN, CCH, 0L, CHW, CHW, 2, 2, 0, flag, bk, 2, NUL, 0L, 0, 1.f,
        stats, gamma, beta, 2, 0);
    gemm_kernel<false, false, true><<<gqkv, blk, 0, stream>>>(Wv, x, v,
        CCH, HWN, CCH, 0L, CHW, CHW, 2, 2, 0, flag, bv, 2, NUL, 0L, 0, 1.f,
        stats, gamma, beta, 2, 0);

    if (batched) {
        // 3) scores = scale * q^T k  (per batch slice via z-stride)
        dim3 gsc(HWN / TILE, HWN / TILE, NBATCH);
        gemm_kernel<true, false, false><<<gsc, blk, 0, stream>>>(q, k, sc,
            HWN, HWN, CCH, CHW, CHW, NN, 0, 0, 1, flag, NUL, 0, NUL, 0L, 0,
            scale, nullptr, NUL, NUL, 0, 0);
        // 4) softmax rows
        softmax_kernel<<<dim3(NBATCH * HWN), blk, 0, stream>>>(sc);
        // 5) hh[c,i] = sum_j v[c,j] attn[i,j]
        gemm_kernel<false, true, false><<<gqkv, blk, 0, stream>>>(v, sc, hh,
            CCH, HWN, HWN, CHW, NN, CHW, 0, 1, 0, flag, NUL, 0, NUL, 0L, 0,
            1.f, nullptr, NUL, NUL, 0, 0);
        // 6) out = Wo hh + bo + x
        gemm_kernel<false, false, false><<<gqkv, blk, 0, stream>>>(Wo, hh, d_out,
            CCH, HWN, CCH, 0L, CHW, CHW, 2, 0, 2, flag, bo, 2, x, CHW, 2, 1.f,
            nullptr, NUL, NUL, 0, 0);
    } else {
        dim3 gsc1(HWN / TILE, HWN / TILE, 1);
        dim3 gpj1(HWN / TILE, CCH / TILE, 1);
        for (int z = 0; z < NBATCH; ++z) {
            gemm_kernel<true, false, false><<<gsc1, blk, 0, stream>>>(q, k, sc,
                HWN, HWN, CCH, CHW, CHW, 0L, 0, 0, 1, flag, NUL, 0, NUL, 0L, 0,
                scale, nullptr, NUL, NUL, 0, z);
            softmax_kernel<<<dim3(HWN), blk, 0, stream>>>(sc);
            gemm_kernel<false, true, false><<<gpj1, blk, 0, stream>>>(v, sc, hh,
                CCH, HWN, HWN, CHW, 0L, 0L, 0, 1, 0, flag, NUL, 0, NUL, 0L, 0,
                1.f, nullptr, NUL, NUL, 0, z);
            gemm_kernel<false, false, false><<<gpj1, blk, 0, stream>>>(Wo, hh, d_out,
                CCH, HWN, CCH, 0L, 0L, CHW, 2, 0, 2, flag, bo, 2, x, CHW, 2, 1.f,
                nullptr, NUL, NUL, 0, z);
        }
    }
}

// Round 4
// 342.782 us; speedup vs baseline: 4.5000x; 4.5000x over previous
//
#include <hip/hip_runtime.h>
#include <hip/hip_bf16.h>

#define HWN    1024
#define CCH    512
#define NBATCH 16
#define NGROUP 32
#define EPSV   1e-5f

using bf16 = __hip_bfloat16;
typedef __attribute__((ext_vector_type(4))) float f32x4;
typedef __attribute__((ext_vector_type(8))) short s16x8;

// Runtime-dtyped element access: c==1 -> fp32, c==0 -> bf16 storage.
__device__ __forceinline__ float ldv(const void* p, long i, int c) {
    return c ? ((const float*)p)[i] : __bfloat162float(((const bf16*)p)[i]);
}
__device__ __forceinline__ void stv(void* p, long i, int c, float v) {
    if (c) ((float*)p)[i] = v;
    else   ((bf16*)p)[i]  = __float2bfloat16(v);
}

// async global->LDS, 16B per lane; lds dest = wave-uniform base + lane*16
__device__ __forceinline__ void glds16(const void* g, void* l) {
    __builtin_amdgcn_global_load_lds(
        (const __attribute__((address_space(1))) void*)g,
        (__attribute__((address_space(3))) void*)l, 16, 0, 0);
}

// ---------------------------------------------------------------------------
// Storage dtype detector (proven in R3). flag=1 => fp32 storage.
// ---------------------------------------------------------------------------
__global__ __launch_bounds__(256) void detect_kernel(const void* __restrict__ x,
                                                     int* __restrict__ flag)
{
    const int tid = threadIdx.x;
    const unsigned short* h = (const unsigned short*)x;
    int ok = 0;
    for (int i = tid; i < 4096; i += 256) {
        int e = (h[2 * i] >> 7) & 0xFF;
        if (e >= 100 && e <= 135) ok++;
    }
    __shared__ int red[256];
    red[tid] = ok; __syncthreads();
    for (int off = 128; off > 0; off >>= 1) {
        if (tid < off) red[tid] += red[tid + off];
        __syncthreads();
    }
    if (tid == 0) flag[0] = (red[0] < 2458) ? 1 : 0;
}

// ---------------------------------------------------------------------------
// GroupNorm stats: one block per (batch, group) -> (mean, rstd).
// ---------------------------------------------------------------------------
__global__ __launch_bounds__(256) void gn_stats_kernel(const void* __restrict__ x,
                                                       const int* __restrict__ flag,
                                                       float2* __restrict__ stats)
{
    const int f = flag[0];
    const int b = blockIdx.x >> 5, g = blockIdx.x & 31;
    const long base = ((long)b * CCH + (long)g * (CCH / NGROUP)) * HWN;
    const int tid = threadIdx.x;
    const int n = (CCH / NGROUP) * HWN;       // 16384
    float s = 0.f, ss = 0.f;
    for (int i = tid; i < n; i += 256) {
        float v = ldv(x, base + i, f);
        s += v; ss += v * v;
    }
    __shared__ float r1[256], r2[256];
    r1[tid] = s; r2[tid] = ss; __syncthreads();
    for (int off = 128; off > 0; off >>= 1) {
        if (tid < off) { r1[tid] += r1[tid + off]; r2[tid] += r2[tid + off]; }
        __syncthreads();
    }
    if (tid == 0) {
        float mean = r1[0] / n;
        float var  = r2[0] / n - mean * mean;
        stats[blockIdx.x] = make_float2(mean, rsqrtf(var + EPSV));
    }
}

// ---------------------------------------------------------------------------
// Weight/bias prep: Wqk = [Wq;Wk] bf16 [1024][512]; Wv,Wo bf16; biases f32.
// ---------------------------------------------------------------------------
__global__ __launch_bounds__(256)
void prep_kernel(const void* __restrict__ Wq, const void* __restrict__ Wk,
                 const void* __restrict__ Wv, const void* __restrict__ Wo,
                 const void* __restrict__ bq, const void* __restrict__ bk,
                 const void* __restrict__ bv, const void* __restrict__ bo,
                 const int* __restrict__ flag,
                 bf16* __restrict__ Wqk, bf16* __restrict__ Wvb, bf16* __restrict__ Wob,
                 float* __restrict__ bQK, float* __restrict__ bV, float* __restrict__ bO)
{
    const int f = flag[0];
    const int idx = blockIdx.x * 256 + threadIdx.x;
    if (idx < 524288) {
        const int r = idx >> 9, c = idx & 511;
        float v = (r < 512) ? ldv(Wq, (long)r * 512 + c, f)
                            : ldv(Wk, (long)(r - 512) * 512 + c, f);
        Wqk[idx] = __float2bfloat16(v);
    } else if (idx < 786432) {
        Wvb[idx - 524288] = __float2bfloat16(ldv(Wv, idx - 524288, f));
    } else if (idx < 1048576) {
        Wob[idx - 786432] = __float2bfloat16(ldv(Wo, idx - 786432, f));
    } else {
        const int j = idx - 1048576;
        if      (j < 512)  bQK[j]        = ldv(bq, j, f);
        else if (j < 1024) bQK[j]        = ldv(bk, j - 512, f);
        else if (j < 1536) bV[j - 1024]  = ldv(bv, j - 1024, f);
        else if (j < 2048) bO[j - 1536]  = ldv(bo, j - 1536, f);
    }
}

// ---------------------------------------------------------------------------
// GN+SiLU with transpose: x [c][i] (flag dtype) -> xn' [i][c] bf16.
// 64x64 LDS tile per block. grid (16, 8, nb). Read batch = zb+z, write batch = z.
// ---------------------------------------------------------------------------
__global__ __launch_bounds__(256)
void gn_apply_kernel(const void* __restrict__ x, const int* __restrict__ flag,
                     const float2* __restrict__ stats,
                     const void* __restrict__ gamma, const void* __restrict__ beta,
                     bf16* __restrict__ xn, int zb)
{
    const int f = flag[0];
    __shared__ float t[64][65];
    const int bz = blockIdx.z;
    const int bx = zb + bz;
    const int i0 = blockIdx.x * 64;
    const int c0 = blockIdx.y * 64;
    const int tid = threadIdx.x;
    const int il = tid & 63;
    const int hq = tid >> 6;              // 0..3
    #pragma unroll
    for (int r = 0; r < 16; ++r) {
        const int cl = r * 4 + hq;
        const int c = c0 + cl;
        const float2 st = stats[bx * NGROUP + (c >> 4)];
        const float ga = ldv(gamma, c, f), be = ldv(beta, c, f);
        float v = ldv(x, (long)bx * CCH * HWN + (long)c * HWN + i0 + il, f);
        v = (v - st.x) * st.y * ga + be;
        t[cl][il] = v / (1.f + __expf(-v));     // SiLU
    }
    __syncthreads();
    #pragma unroll
    for (int r = 0; r < 16; ++r) {
        const int ii = r * 4 + hq;
        xn[(long)bz * CCH * HWN + (long)(i0 + ii) * CCH + c0 + il] =
            __float2bfloat16(t[il][ii]);
    }
}

// ---------------------------------------------------------------------------
// MFMA TN GEMM: C[m][n] = alpha * sum_k A[m][k] * B[n][k]  (+rowBias[m]
// +colBias[n]) (+resid, FINAL). A: [M][K] row-major lda; B: [N][K] row-major
// ldb (i.e. B^T layout). 128x128 tile, BK=32, 4 waves, 16x16x32 bf16 MFMA.
// Batch: zA = z0 + blockIdx.z; element strides sA/sB/sC/sR (0 = shared).
// ---------------------------------------------------------------------------
template<bool FINAL>
__global__ __launch_bounds__(256)
void mfma_gemm(const bf16* __restrict__ A, const bf16* __restrict__ B,
               void* __restrict__ C, int K,
               int lda, int ldb, int ldc,
               long sA, long sB, long sC, int z0,
               const float* __restrict__ rowBias, const float* __restrict__ colBias,
               float alpha, const void* __restrict__ resid, long sR,
               const int* __restrict__ flag)
{
    __shared__ bf16 lA[128 * 32];
    __shared__ bf16 lB[128 * 32];

    const int tid = threadIdx.x;
    const int w   = tid >> 6;         // wave 0..3
    const int l   = tid & 63;
    const int ln  = l & 15;
    const int qd  = l >> 4;           // 0..3
    const int wm  = (w >> 1) * 64;    // wave sub-tile origin
    const int wn  = (w & 1) * 64;
    const int zA  = z0 + blockIdx.z;

    const bf16* Ab = A + (long)zA * sA;
    const bf16* Bb = B + (long)zA * sB;
    const int m0 = blockIdx.y * 128;
    const int n0 = blockIdx.x * 128;

    // staging: lane -> row (l>>2), 16B seg (l&3)
    const int sr = l >> 2;
    const int sc = (l & 3) * 8;
    const bf16* gA0 = Ab + (long)(m0 + w * 16 + sr) * lda + sc;
    const bf16* gA1 = gA0 + (long)64 * lda;
    const bf16* gB0 = Bb + (long)(n0 + w * 16 + sr) * ldb + sc;
    const bf16* gB1 = gB0 + (long)64 * ldb;
    bf16* dA0 = lA + w * 512;          // wave-uniform LDS bases
    bf16* dA1 = lA + 2048 + w * 512;
    bf16* dB0 = lB + w * 512;
    bf16* dB1 = lB + 2048 + w * 512;

    f32x4 acc[4][4];
    #pragma unroll
    for (int i = 0; i < 4; ++i)
        #pragma unroll
        for (int j = 0; j < 4; ++j)
            acc[i][j] = (f32x4){0.f, 0.f, 0.f, 0.f};

    for (int kk = 0; kk < K; kk += 32) {
        glds16(gA0 + kk, dA0);
        glds16(gA1 + kk, dA1);
        glds16(gB0 + kk, dB0);
        glds16(gB1 + kk, dB1);
        __syncthreads();

        s16x8 af[4], bf[4];
        #pragma unroll
        for (int i = 0; i < 4; ++i)
            af[i] = *(const s16x8*)&lA[(wm + i * 16 + ln) * 32 + qd * 8];
        #pragma unroll
        for (int j = 0; j < 4; ++j)
            bf[j] = *(const s16x8*)&lB[(wn + j * 16 + ln) * 32 + qd * 8];
        #pragma unroll
        for (int i = 0; i < 4; ++i)
            #pragma unroll
            for (int j = 0; j < 4; ++j)
                acc[i][j] = __builtin_amdgcn_mfma_f32_16x16x32_bf16(
                    af[i], bf[j], acc[i][j], 0, 0, 0);
        __syncthreads();
    }

    // epilogue: C/D layout col = lane&15, row = qd*4 + reg  [m89]
    const int f = (FINAL && flag) ? flag[0] : 0;
    #pragma unroll
    for (int i = 0; i < 4; ++i) {
        #pragma unroll
        for (int j = 0; j < 4; ++j) {
            const int mBase = m0 + wm + i * 16 + qd * 4;
            const int n = n0 + wn + j * 16 + ln;
            const float cb = colBias ? colBias[n] : 0.f;
            #pragma unroll
            for (int r = 0; r < 4; ++r) {
                const int m = mBase + r;
                float v = alpha * acc[i][j][r] + cb;
                if (rowBias) v += rowBias[m];
                const long idx = (long)zA * sC + (long)m * ldc + n;
                if (FINAL) {
                    if (resid) v += ldv(resid, (long)zA * sR + (long)m * ldc + n, f);
                    stv(C, idx, f, v);
                } else {
                    ((bf16*)C)[idx] = __float2bfloat16(v);
                }
            }
        }
    }
}

// ---------------------------------------------------------------------------
// Row softmax over 1024 bf16, in place. One block per row.
// ---------------------------------------------------------------------------
__global__ __launch_bounds__(256)
void softmax_kernel(bf16* __restrict__ S)
{
    bf16* p = S + (long)blockIdx.x * HWN;
    const int tid = threadIdx.x;
    float v[4];
    float mx = -1e30f;
    #pragma unroll
    for (int i = 0; i < 4; ++i) {
        v[i] = __bfloat162float(p[tid + 256 * i]);
        mx = fmaxf(mx, v[i]);
    }
    __shared__ float red[256];
    red[tid] = mx; __syncthreads();
    for (int off = 128; off > 0; off >>= 1) {
        if (tid < off) red[tid] = fmaxf(red[tid], red[tid + off]);
        __syncthreads();
    }
    mx = red[0]; __syncthreads();
    float s = 0.f;
    #pragma unroll
    for (int i = 0; i < 4; ++i) { v[i] = __expf(v[i] - mx); s += v[i]; }
    red[tid] = s; __syncthreads();
    for (int off = 128; off > 0; off >>= 1) {
        if (tid < off) red[tid] += red[tid + off];
        __syncthreads();
    }
    const float inv = 1.f / red[0];
    #pragma unroll
    for (int i = 0; i < 4; ++i) p[tid + 256 * i] = __float2bfloat16(v[i] * inv);
}

// ---------------------------------------------------------------------------
extern "C" void kernel_launch(void* const* d_in, const int* in_sizes, int n_in,
                              void* d_out, int out_size, void* d_ws, size_t ws_size,
                              hipStream_t stream)
{
    // input order (insertion per docs; alphabetical fallback) — proven in R3
    const long NX = (long)NBATCH * CCH * HWN;
    int ix, iWq, ibq, iWk, ibk, iWv, ibv, iWo, ibo, iga, ibe;
    if (in_sizes[0] == NX) {
        ix = 0; iWq = 1; ibq = 2; iWk = 3; ibk = 4; iWv = 5; ibv = 6;
        iWo = 7; ibo = 8; iga = 9; ibe = 10;
    } else {
        iWk = 0; iWo = 1; iWq = 2; iWv = 3; ibe = 4; ibk = 5; ibo = 6;
        ibq = 7; ibv = 8; iga = 9; ix = 10;
    }
    const void* x     = d_in[ix];
    const void* Wq    = d_in[iWq];
    const void* bq    = d_in[ibq];
    const void* Wk    = d_in[iWk];
    const void* bk    = d_in[ibk];
    const void* Wv    = d_in[iWv];
    const void* bv    = d_in[ibv];
    const void* Wo    = d_in[iWo];
    const void* bo    = d_in[ibo];
    const void* gamma = d_in[iga];
    const void* beta  = d_in[ibe];

    const long CHW = (long)CCH * HWN;      // 524288
    const long NN  = (long)HWN * HWN;      // 1048576
    const size_t MB = 1ull << 20;
    char* ws = (char*)d_ws;

    bf16*   Wqk   = (bf16*)ws;                         // 1 MB
    bf16*   Wvb   = (bf16*)(ws + MB);                  // 0.5 MB
    bf16*   Wob   = (bf16*)(ws + MB + MB / 2);         // 0.5 MB
    float*  bQK   = (float*)(ws + 2 * MB);
    float*  bV    = (float*)(ws + 2 * MB + 4096);
    float*  bO    = (float*)(ws + 2 * MB + 6144);
    float2* stats = (float2*)(ws + 2 * MB + 8192);
    int*    flag  = (int*)(ws + 2 * MB + 12288);

    dim3 blk(256);
    const float scale = 0.044194173824159216f;   // 512^-0.5
    const float* FNUL = nullptr;
    const void*  VNUL = nullptr;

    detect_kernel<<<dim3(1), blk, 0, stream>>>(x, flag);
    gn_stats_kernel<<<dim3(NBATCH * NGROUP), blk, 0, stream>>>(x, flag, stats);
    prep_kernel<<<dim3(4104), blk, 0, stream>>>(Wq, Wk, Wv, Wo, bq, bk, bv, bo,
                                                flag, Wqk, Wvb, Wob, bQK, bV, bO);

    const int tier = (ws_size >= 100 * MB) ? 1 : (ws_size >= 70 * MB) ? 2 : 3;

    if (tier <= 2) {
        bf16* xn = (bf16*)(ws + 3 * MB);      // 16 MB [i][c] per batch
        bf16* V  = (bf16*)(ws + 19 * MB);     // 16 MB [c][j] per batch
        bf16* QK = (bf16*)(ws + 35 * MB);     // 32 MB [i][1024] per batch
        bf16* S  = (bf16*)(ws + 67 * MB);     // 32 MB (tier1) / 2 MB (tier2)
        bf16* O  = xn;                        // overlay: xn dead after V GEMM

        gn_apply_kernel<<<dim3(16, 8, NBATCH), blk, 0, stream>>>(
            x, flag, stats, gamma, beta, xn, 0);

        // QK' = xn' @ [Wq;Wk]^T + bias  (M=1024,N=1024,K=512)
        mfma_gemm<false><<<dim3(8, 8, NBATCH), blk, 0, stream>>>(
            xn, Wqk, QK, 512, 512, 512, 1024, CHW, 0L, NN, 0,
            FNUL, bQK, 1.f, VNUL, 0L, nullptr);
        // V[c][j] = Wv @ gn(x): A=Wv, B=xn'  (M=512,N=1024,K=512)
        mfma_gemm<false><<<dim3(8, 4, NBATCH), blk, 0, stream>>>(
            Wvb, xn, V, 512, 512, 512, 1024, 0L, CHW, CHW, 0,
            bV, FNUL, 1.f, VNUL, 0L, nullptr);

        if (tier == 1) {
            // S = scale * Q' K'^T  (M=N=1024,K=512)
            mfma_gemm<false><<<dim3(8, 8, NBATCH), blk, 0, stream>>>(
                QK, QK + 512, S, 512, 1024, 1024, 1024, NN, NN, NN, 0,
                FNUL, FNUL, scale, VNUL, 0L, nullptr);
            softmax_kernel<<<dim3(NBATCH * HWN), blk, 0, stream>>>(S);
            // O' = P @ V^T  (M=1024,N=512,K=1024)
            mfma_gemm<false><<<dim3(4, 8, NBATCH), blk, 0, stream>>>(
                S, V, O, 1024, 1024, 1024, 512, NN, CHW, CHW, 0,
                FNUL, FNUL, 1.f, VNUL, 0L, nullptr);
        } else {
            for (int b = 0; b < NBATCH; ++b) {
                mfma_gemm<false><<<dim3(8, 8, 1), blk, 0, stream>>>(
                    QK, QK + 512, S, 512, 1024, 1024, 1024, NN, NN, 0L, b,
                    FNUL, FNUL, scale, VNUL, 0L, nullptr);
                softmax_kernel<<<dim3(HWN), blk, 0, stream>>>(S);
                mfma_gemm<false><<<dim3(4, 8, 1), blk, 0, stream>>>(
                    S, V, O, 1024, 1024, 1024, 512, 0L, CHW, CHW, b,
                    FNUL, FNUL, 1.f, VNUL, 0L, nullptr);
            }
        }
        // out = Wo @ O'^T + bo + x  (M=512,N=1024,K=512), flag-dtype store
        mfma_gemm<true><<<dim3(8, 4, NBATCH), blk, 0, stream>>>(
            Wob, O, d_out, 512, 512, 512, 1024, 0L, CHW, CHW, 0,
            bO, FNUL, 1.f, x, CHW, flag);
    } else {
        // tier 3: fully per-batch (ws >= 9 MB)
        bf16* xn = (bf16*)(ws + 3 * MB);      // 1 MB
        bf16* V  = (bf16*)(ws + 4 * MB);      // 1 MB
        bf16* QK = (bf16*)(ws + 5 * MB);      // 2 MB
        bf16* S  = (bf16*)(ws + 7 * MB);      // 2 MB
        bf16* O  = xn;
        for (int b = 0; b < NBATCH; ++b) {
            gn_apply_kernel<<<dim3(16, 8, 1), blk, 0, stream>>>(
                x, flag, stats, gamma, beta, xn, b);
            mfma_gemm<false><<<dim3(8, 8, 1), blk, 0, stream>>>(
                xn, Wqk, QK, 512, 512, 512, 1024, 0L, 0L, 0L, 0,
                FNUL, bQK, 1.f, VNUL, 0L, nullptr);
            mfma_gemm<false><<<dim3(8, 4, 1), blk, 0, stream>>>(
                Wvb, xn, V, 512, 512, 512, 1024, 0L, 0L, 0L, 0,
                bV, FNUL, 1.f, VNUL, 0L, nullptr);
            mfma_gemm<false><<<dim3(8, 8, 1), blk, 0, stream>>>(
                QK, QK + 512, S, 512, 1024, 1024, 1024, 0L, 0L, 0L, 0,
                FNUL, FNUL, scale, VNUL, 0L, nullptr);
            softmax_kernel<<<dim3(HWN), blk, 0, stream>>>(S);
            mfma_gemm<false><<<dim3(4, 8, 1), blk, 0, stream>>>(
                S, V, O, 1024, 1024, 1024, 512, 0L, 0L, 0L, 0,
                FNUL, FNUL, 1.f, VNUL, 0L, nullptr);
            mfma_gemm<true><<<dim3(8, 4, 1), blk, 0, stream>>>(
                Wob, O, d_out, 512, 512, 512, 1024, 0L, 0L, CHW, b,
                bO, FNUL, 1.f, x, CHW, flag);
        }
    }
}

// Round 5
// 330.693 us; speedup vs baseline: 4.6644x; 1.0366x over previous
//
#include <hip/hip_runtime.h>
#include <hip/hip_bf16.h>

#define HWN    1024
#define CCH    512
#define NBATCH 16
#define NGROUP 32
#define EPSV   1e-5f

using bf16 = __hip_bfloat16;
typedef __attribute__((ext_vector_type(4))) float f32x4;
typedef __attribute__((ext_vector_type(8))) short s16x8;

// Runtime-dtyped element access: c==1 -> fp32, c==0 -> bf16 storage.
__device__ __forceinline__ float ldv(const void* p, long i, int c) {
    return c ? ((const float*)p)[i] : __bfloat162float(((const bf16*)p)[i]);
}
__device__ __forceinline__ void stv(void* p, long i, int c, float v) {
    if (c) ((float*)p)[i] = v;
    else   ((bf16*)p)[i]  = __float2bfloat16(v);
}
__device__ __forceinline__ float b2f(unsigned short h) {
    union { float f; unsigned u; } c; c.u = ((unsigned)h) << 16; return c.f;
}
__device__ __forceinline__ unsigned short f2b(float v) {
    bf16 b = __float2bfloat16(v);
    return *(unsigned short*)&b;
}

// async global->LDS, 16B per lane; lds dest = wave-uniform base + lane*16
__device__ __forceinline__ void glds16(const void* g, void* l) {
    __builtin_amdgcn_global_load_lds(
        (const __attribute__((address_space(1))) void*)g,
        (__attribute__((address_space(3))) void*)l, 16, 0, 0);
}

// ---------------------------------------------------------------------------
// Storage dtype detector (proven in R3). flag=1 => fp32 storage.
// ---------------------------------------------------------------------------
__global__ __launch_bounds__(256) void detect_kernel(const void* __restrict__ x,
                                                     int* __restrict__ flag)
{
    const int tid = threadIdx.x;
    const unsigned short* h = (const unsigned short*)x;
    int ok = 0;
    for (int i = tid; i < 4096; i += 256) {
        int e = (h[2 * i] >> 7) & 0xFF;
        if (e >= 100 && e <= 135) ok++;
    }
    __shared__ int red[256];
    red[tid] = ok; __syncthreads();
    for (int off = 128; off > 0; off >>= 1) {
        if (tid < off) red[tid] += red[tid + off];
        __syncthreads();
    }
    if (tid == 0) flag[0] = (red[0] < 2458) ? 1 : 0;
}

// ---------------------------------------------------------------------------
// GroupNorm stats: one block per (batch, group) -> (mean, rstd).
// ---------------------------------------------------------------------------
__global__ __launch_bounds__(256) void gn_stats_kernel(const void* __restrict__ x,
                                                       const int* __restrict__ flag,
                                                       float2* __restrict__ stats)
{
    const int f = flag[0];
    const int b = blockIdx.x >> 5, g = blockIdx.x & 31;
    const long base = ((long)b * CCH + (long)g * (CCH / NGROUP)) * HWN;
    const int tid = threadIdx.x;
    const int n = (CCH / NGROUP) * HWN;       // 16384
    float s = 0.f, ss = 0.f;
    for (int i = tid; i < n; i += 256) {
        float v = ldv(x, base + i, f);
        s += v; ss += v * v;
    }
    __shared__ float r1[256], r2[256];
    r1[tid] = s; r2[tid] = ss; __syncthreads();
    for (int off = 128; off > 0; off >>= 1) {
        if (tid < off) { r1[tid] += r1[tid + off]; r2[tid] += r2[tid + off]; }
        __syncthreads();
    }
    if (tid == 0) {
        float mean = r1[0] / n;
        float var  = r2[0] / n - mean * mean;
        stats[blockIdx.x] = make_float2(mean, rsqrtf(var + EPSV));
    }
}

// ---------------------------------------------------------------------------
// Weight/bias prep: Wqk = [Wq;Wk] bf16 [1024][512]; Wv,Wo bf16; biases f32.
// ---------------------------------------------------------------------------
__global__ __launch_bounds__(256)
void prep_kernel(const void* __restrict__ Wq, const void* __restrict__ Wk,
                 const void* __restrict__ Wv, const void* __restrict__ Wo,
                 const void* __restrict__ bq, const void* __restrict__ bk,
                 const void* __restrict__ bv, const void* __restrict__ bo,
                 const int* __restrict__ flag,
                 bf16* __restrict__ Wqk, bf16* __restrict__ Wvb, bf16* __restrict__ Wob,
                 float* __restrict__ bQK, float* __restrict__ bV, float* __restrict__ bO)
{
    const int f = flag[0];
    const int idx = blockIdx.x * 256 + threadIdx.x;
    if (idx < 524288) {
        const int r = idx >> 9, c = idx & 511;
        float v = (r < 512) ? ldv(Wq, (long)r * 512 + c, f)
                            : ldv(Wk, (long)(r - 512) * 512 + c, f);
        Wqk[idx] = __float2bfloat16(v);
    } else if (idx < 786432) {
        Wvb[idx - 524288] = __float2bfloat16(ldv(Wv, idx - 524288, f));
    } else if (idx < 1048576) {
        Wob[idx - 786432] = __float2bfloat16(ldv(Wo, idx - 786432, f));
    } else {
        const int j = idx - 1048576;
        if      (j < 512)  bQK[j]        = ldv(bq, j, f);
        else if (j < 1024) bQK[j]        = ldv(bk, j - 512, f);
        else if (j < 1536) bV[j - 1024]  = ldv(bv, j - 1024, f);
        else if (j < 2048) bO[j - 1536]  = ldv(bo, j - 1536, f);
    }
}

// ---------------------------------------------------------------------------
// GN+SiLU with transpose: x [c][i] (flag dtype) -> xn' [i][c] bf16.
// ---------------------------------------------------------------------------
__global__ __launch_bounds__(256)
void gn_apply_kernel(const void* __restrict__ x, const int* __restrict__ flag,
                     const float2* __restrict__ stats,
                     const void* __restrict__ gamma, const void* __restrict__ beta,
                     bf16* __restrict__ xn, int zb)
{
    const int f = flag[0];
    __shared__ float t[64][65];
    const int bz = blockIdx.z;
    const int bx = zb + bz;
    const int i0 = blockIdx.x * 64;
    const int c0 = blockIdx.y * 64;
    const int tid = threadIdx.x;
    const int il = tid & 63;
    const int hq = tid >> 6;              // 0..3
    #pragma unroll
    for (int r = 0; r < 16; ++r) {
        const int cl = r * 4 + hq;
        const int c = c0 + cl;
        const float2 st = stats[bx * NGROUP + (c >> 4)];
        const float ga = ldv(gamma, c, f), be = ldv(beta, c, f);
        float v = ldv(x, (long)bx * CCH * HWN + (long)c * HWN + i0 + il, f);
        v = (v - st.x) * st.y * ga + be;
        t[cl][il] = v / (1.f + __expf(-v));     // SiLU
    }
    __syncthreads();
    #pragma unroll
    for (int r = 0; r < 16; ++r) {
        const int ii = r * 4 + hq;
        xn[(long)bz * CCH * HWN + (long)(i0 + ii) * CCH + c0 + il] =
            __float2bfloat16(t[il][ii]);
    }
}

// ---------------------------------------------------------------------------
// MFMA TN GEMM: C[m][n] = alpha * sum_k A[m][k] * B[n][k]  (+rowBias[m]
// +colBias[n]) (+resid, FINAL). 128x128 tile, BK=32, 4 waves, 16x16x32 bf16.
// Double-buffered LDS (DMA tile k+1 overlaps compute on tile k).
// XOR bank swizzle: LDS (row, slot) holds global kseg = slot ^ ((row>>1)&3),
// applied on the global-read side (global_load_lds needs lane-contiguous LDS).
// ---------------------------------------------------------------------------
template<bool FINAL>
__global__ __launch_bounds__(256)
void mfma_gemm(const bf16* __restrict__ A, const bf16* __restrict__ B,
               void* __restrict__ C, int K,
               int lda, int ldb, int ldc,
               long sA, long sB, long sC, int z0,
               const float* __restrict__ rowBias, const float* __restrict__ colBias,
               float alpha, const void* __restrict__ resid, long sR,
               const int* __restrict__ flag)
{
    __shared__ bf16 lA[2][128 * 32];
    __shared__ bf16 lB[2][128 * 32];

    const int tid = threadIdx.x;
    const int w   = tid >> 6;         // wave 0..3
    const int l   = tid & 63;
    const int ln  = l & 15;
    const int qd  = l >> 4;           // 0..3
    const int wm  = (w >> 1) * 64;
    const int wn  = (w & 1) * 64;
    const int zA  = z0 + blockIdx.z;

    const bf16* Ab = A + (long)zA * sA;
    const bf16* Bb = B + (long)zA * sB;
    const int m0 = blockIdx.y * 128;
    const int n0 = blockIdx.x * 128;

    // staging: lane -> local row l>>2, LDS slot l&3 which holds swizzled kseg
    const int sr   = l >> 2;
    const int kswz = ((l & 3) ^ ((l >> 3) & 3)) * 8;   // global col offset
    const bf16* gA0 = Ab + (long)(m0 + w * 16 + sr) * lda + kswz;
    const bf16* gA1 = gA0 + (long)64 * lda;
    const bf16* gB0 = Bb + (long)(n0 + w * 16 + sr) * ldb + kswz;
    const bf16* gB1 = gB0 + (long)64 * ldb;

    f32x4 acc[4][4];
    #pragma unroll
    for (int i = 0; i < 4; ++i)
        #pragma unroll
        for (int j = 0; j < 4; ++j)
            acc[i][j] = (f32x4){0.f, 0.f, 0.f, 0.f};

    // swizzled fragment read offsets (element units); 2-way bank aliasing only
    const int swA = (qd ^ ((ln >> 1) & 3)) * 8;

    // prologue: stage tile 0 into buffer 0
    glds16(gA0, &lA[0][w * 512]);
    glds16(gA1, &lA[0][2048 + w * 512]);
    glds16(gB0, &lB[0][w * 512]);
    glds16(gB1, &lB[0][2048 + w * 512]);

    const int NK = K >> 5;
    for (int t = 0; t < NK; ++t) {
        const int p = t & 1;
        __syncthreads();               // drains vmcnt: tile t resident; prior reads done
        if (t + 1 < NK) {              // stage tile t+1 into other buffer (overlaps MFMA)
            const int kk = (t + 1) << 5;
            glds16(gA0 + kk, &lA[p ^ 1][w * 512]);
            glds16(gA1 + kk, &lA[p ^ 1][2048 + w * 512]);
            glds16(gB0 + kk, &lB[p ^ 1][w * 512]);
            glds16(gB1 + kk, &lB[p ^ 1][2048 + w * 512]);
        }
        s16x8 af[4], bfr[4];
        #pragma unroll
        for (int i = 0; i < 4; ++i)
            af[i] = *(const s16x8*)&lA[p][(wm + i * 16 + ln) * 32 + swA];
        #pragma unroll
        for (int j = 0; j < 4; ++j)
            bfr[j] = *(const s16x8*)&lB[p][(wn + j * 16 + ln) * 32 + swA];
        #pragma unroll
        for (int i = 0; i < 4; ++i)
            #pragma unroll
            for (int j = 0; j < 4; ++j)
                acc[i][j] = __builtin_amdgcn_mfma_f32_16x16x32_bf16(
                    af[i], bfr[j], acc[i][j], 0, 0, 0);
    }

    // epilogue: C/D layout col = lane&15, row = qd*4 + reg  [m89]
    const int f = (FINAL && flag) ? flag[0] : 0;
    #pragma unroll
    for (int i = 0; i < 4; ++i) {
        #pragma unroll
        for (int j = 0; j < 4; ++j) {
            const int mBase = m0 + wm + i * 16 + qd * 4;
            const int n = n0 + wn + j * 16 + ln;
            const float cb = colBias ? colBias[n] : 0.f;
            #pragma unroll
            for (int r = 0; r < 4; ++r) {
                const int m = mBase + r;
                float v = alpha * acc[i][j][r] + cb;
                if (rowBias) v += rowBias[m];
                const long idx = (long)zA * sC + (long)m * ldc + n;
                if (FINAL) {
                    if (resid) v += ldv(resid, (long)zA * sR + (long)m * ldc + n, f);
                    stv(C, idx, f, v);
                } else {
                    ((bf16*)C)[idx] = __float2bfloat16(v);
                }
            }
        }
    }
}

// ---------------------------------------------------------------------------
// Row softmax over 1024 bf16, in place. One block per row, ushort4 vectorized.
// ---------------------------------------------------------------------------
__global__ __launch_bounds__(256)
void softmax_kernel(bf16* __restrict__ S)
{
    ushort4* p = (ushort4*)(S + (long)blockIdx.x * HWN);
    const int tid = threadIdx.x;
    ushort4 u = p[tid];
    float v[4] = { b2f(u.x), b2f(u.y), b2f(u.z), b2f(u.w) };
    float mx = fmaxf(fmaxf(v[0], v[1]), fmaxf(v[2], v[3]));

    __shared__ float red[256];
    red[tid] = mx; __syncthreads();
    for (int off = 128; off > 0; off >>= 1) {
        if (tid < off) red[tid] = fmaxf(red[tid], red[tid + off]);
        __syncthreads();
    }
    mx = red[0]; __syncthreads();
    float s = 0.f;
    #pragma unroll
    for (int i = 0; i < 4; ++i) { v[i] = __expf(v[i] - mx); s += v[i]; }
    red[tid] = s; __syncthreads();
    for (int off = 128; off > 0; off >>= 1) {
        if (tid < off) red[tid] += red[tid + off];
        __syncthreads();
    }
    const float inv = 1.f / red[0];
    u.x = f2b(v[0] * inv); u.y = f2b(v[1] * inv);
    u.z = f2b(v[2] * inv); u.w = f2b(v[3] * inv);
    p[tid] = u;
}

// ---------------------------------------------------------------------------
extern "C" void kernel_launch(void* const* d_in, const int* in_sizes, int n_in,
                              void* d_out, int out_size, void* d_ws, size_t ws_size,
                              hipStream_t stream)
{
    // input order (insertion per docs; alphabetical fallback) — proven in R3
    const long NX = (long)NBATCH * CCH * HWN;
    int ix, iWq, ibq, iWk, ibk, iWv, ibv, iWo, ibo, iga, ibe;
    if (in_sizes[0] == NX) {
        ix = 0; iWq = 1; ibq = 2; iWk = 3; ibk = 4; iWv = 5; ibv = 6;
        iWo = 7; ibo = 8; iga = 9; ibe = 10;
    } else {
        iWk = 0; iWo = 1; iWq = 2; iWv = 3; ibe = 4; ibk = 5; ibo = 6;
        ibq = 7; ibv = 8; iga = 9; ix = 10;
    }
    const void* x     = d_in[ix];
    const void* Wq    = d_in[iWq];
    const void* bq    = d_in[ibq];
    const void* Wk    = d_in[iWk];
    const void* bk    = d_in[ibk];
    const void* Wv    = d_in[iWv];
    const void* bv    = d_in[ibv];
    const void* Wo    = d_in[iWo];
    const void* bo    = d_in[ibo];
    const void* gamma = d_in[iga];
    const void* beta  = d_in[ibe];

    const long CHW = (long)CCH * HWN;      // 524288
    const long NN  = (long)HWN * HWN;      // 1048576
    const size_t MB = 1ull << 20;
    char* ws = (char*)d_ws;

    bf16*   Wqk   = (bf16*)ws;                         // 1 MB
    bf16*   Wvb   = (bf16*)(ws + MB);                  // 0.5 MB
    bf16*   Wob   = (bf16*)(ws + MB + MB / 2);         // 0.5 MB
    float*  bQK   = (float*)(ws + 2 * MB);
    float*  bV    = (float*)(ws + 2 * MB + 4096);
    float*  bO    = (float*)(ws + 2 * MB + 6144);
    float2* stats = (float2*)(ws + 2 * MB + 8192);
    int*    flag  = (int*)(ws + 2 * MB + 12288);

    dim3 blk(256);
    const float scale = 0.044194173824159216f;   // 512^-0.5
    const float* FNUL = nullptr;
    const void*  VNUL = nullptr;

    detect_kernel<<<dim3(1), blk, 0, stream>>>(x, flag);
    gn_stats_kernel<<<dim3(NBATCH * NGROUP), blk, 0, stream>>>(x, flag, stats);
    prep_kernel<<<dim3(4104), blk, 0, stream>>>(Wq, Wk, Wv, Wo, bq, bk, bv, bo,
                                                flag, Wqk, Wvb, Wob, bQK, bV, bO);

    const int tier = (ws_size >= 100 * MB) ? 1 : (ws_size >= 70 * MB) ? 2 : 3;

    if (tier <= 2) {
        bf16* xn = (bf16*)(ws + 3 * MB);      // 16 MB [i][c] per batch
        bf16* V  = (bf16*)(ws + 19 * MB);     // 16 MB [c][j] per batch
        bf16* QK = (bf16*)(ws + 35 * MB);     // 32 MB [i][1024] per batch
        bf16* S  = (bf16*)(ws + 67 * MB);     // 32 MB (tier1) / 2 MB (tier2)
        bf16* O  = xn;                        // overlay: xn dead after V GEMM

        gn_apply_kernel<<<dim3(16, 8, NBATCH), blk, 0, stream>>>(
            x, flag, stats, gamma, beta, xn, 0);

        // QK' = xn' @ [Wq;Wk]^T + bias  (M=1024,N=1024,K=512)
        mfma_gemm<false><<<dim3(8, 8, NBATCH), blk, 0, stream>>>(
            xn, Wqk, QK, 512, 512, 512, 1024, CHW, 0L, NN, 0,
            FNUL, bQK, 1.f, VNUL, 0L, nullptr);
        // V[c][j] = Wv @ gn(x): A=Wv, B=xn'  (M=512,N=1024,K=512)
        mfma_gemm<false><<<dim3(8, 4, NBATCH), blk, 0, stream>>>(
            Wvb, xn, V, 512, 512, 512, 1024, 0L, CHW, CHW, 0,
            bV, FNUL, 1.f, VNUL, 0L, nullptr);

        if (tier == 1) {
            // S = scale * Q' K'^T  (M=N=1024,K=512)
            mfma_gemm<false><<<dim3(8, 8, NBATCH), blk, 0, stream>>>(
                QK, QK + 512, S, 512, 1024, 1024, 1024, NN, NN, NN, 0,
                FNUL, FNUL, scale, VNUL, 0L, nullptr);
            softmax_kernel<<<dim3(NBATCH * HWN), blk, 0, stream>>>(S);
            // O' = P @ V^T  (M=1024,N=512,K=1024)
            mfma_gemm<false><<<dim3(4, 8, NBATCH), blk, 0, stream>>>(
                S, V, O, 1024, 1024, 1024, 512, NN, CHW, CHW, 0,
                FNUL, FNUL, 1.f, VNUL, 0L, nullptr);
        } else {
            for (int b = 0; b < NBATCH; ++b) {
                mfma_gemm<false><<<dim3(8, 8, 1), blk, 0, stream>>>(
                    QK, QK + 512, S, 512, 1024, 1024, 1024, NN, NN, 0L, b,
                    FNUL, FNUL, scale, VNUL, 0L, nullptr);
                softmax_kernel<<<dim3(HWN), blk, 0, stream>>>(S);
                mfma_gemm<false><<<dim3(4, 8, 1), blk, 0, stream>>>(
                    S, V, O, 1024, 1024, 1024, 512, 0L, CHW, CHW, b,
                    FNUL, FNUL, 1.f, VNUL, 0L, nullptr);
            }
        }
        // out = Wo @ O'^T + bo + x  (M=512,N=1024,K=512), flag-dtype store
        mfma_gemm<true><<<dim3(8, 4, NBATCH), blk, 0, stream>>>(
            Wob, O, d_out, 512, 512, 512, 1024, 0L, CHW, CHW, 0,
            bO, FNUL, 1.f, x, CHW, flag);
    } else {
        // tier 3: fully per-batch (ws >= 9 MB)
        bf16* xn = (bf16*)(ws + 3 * MB);      // 1 MB
        bf16* V  = (bf16*)(ws + 4 * MB);      // 1 MB
        bf16* QK = (bf16*)(ws + 5 * MB);      // 2 MB
        bf16* S  = (bf16*)(ws + 7 * MB);      // 2 MB
        bf16* O  = xn;
        for (int b = 0; b < NBATCH; ++b) {
            gn_apply_kernel<<<dim3(16, 8, 1), blk, 0, stream>>>(
                x, flag, stats, gamma, beta, xn, b);
            mfma_gemm<false><<<dim3(8, 8, 1), blk, 0, stream>>>(
                xn, Wqk, QK, 512, 512, 512, 1024, 0L, 0L, 0L, 0,
                FNUL, bQK, 1.f, VNUL, 0L, nullptr);
            mfma_gemm<false><<<dim3(8, 4, 1), blk, 0, stream>>>(
                Wvb, xn, V, 512, 512, 512, 1024, 0L, 0L, 0L, 0,
                bV, FNUL, 1.f, VNUL, 0L, nullptr);
            mfma_gemm<false><<<dim3(8, 8, 1), blk, 0, stream>>>(
                QK, QK + 512, S, 512, 1024, 1024, 1024, 0L, 0L, 0L, 0,
                FNUL, FNUL, scale, VNUL, 0L, nullptr);
            softmax_kernel<<<dim3(HWN), blk, 0, stream>>>(S);
            mfma_gemm<false><<<dim3(4, 8, 1), blk, 0, stream>>>(
                S, V, O, 1024, 1024, 1024, 512, 0L, 0L, 0L, 0,
                FNUL, FNUL, 1.f, VNUL, 0L, nullptr);
            mfma_gemm<true><<<dim3(8, 4, 1), blk, 0, stream>>>(
                Wob, O, d_out, 512, 512, 512, 1024, 0L, 0L, CHW, b,
                bO, FNUL, 1.f, x, CHW, flag);
        }
    }
}